// Round 14
// baseline (42.415 us; speedup 1.0000x reference)
//
#include <hip/hip_runtime.h>
#include <hip/hip_bf16.h>
#include <math.h>

#define KC 32
#define DC 128
#define QC 16
#define NPTS 20000

// ws layout (bytes):
//   c2p[32] f32        @ 0
//   btG[544*128] bf16  @ 128     (PRE-SWIZZLED: elem (gr,col) at seg^(gr&15))
//   s2h[20000] f32     @ 139392  (0.5 * x^T invpsi x)
//   XH[1250*2048] s    @ 219520  (fragment-major bf16 X)
#define WS_C2P_B 0
#define WS_BTG_B 128
#define WS_S2_B  139392
#define WS_XH_B  219520

typedef __attribute__((ext_vector_type(8))) short bf16x8;
typedef __attribute__((ext_vector_type(4))) float f32x4;

// round-to-nearest-even bf16
static __device__ __forceinline__ short f2bf(float x) {
    union { float f; unsigned u; } v; v.f = x;
    unsigned r = v.u + 0x7fffu + ((v.u >> 16) & 1u);
    return (short)(r >> 16);
}

// ---------------------------------------------------------------------------
// Kernel 1 (fused prep): blocks 0..31 per-component Woodbury precompute
// (G/sqrt2 + w' rows, bf16, PRE-SWIZZLED column layout; C2'); blocks 32+
// convert 64 X rows each to bf16 fragment-major and store 0.5*x^T invpsi x.
// ---------------------------------------------------------------------------
__global__ __launch_bounds__(256) void mfa_prep(
    const float* __restrict__ X, const float* __restrict__ log_pi,
    const float* __restrict__ mu, const float* __restrict__ Lam,
    const float* __restrict__ log_psi,
    float* __restrict__ c2p, short* __restrict__ btG,
    short* __restrict__ xH, float* __restrict__ s2g)
{
    int t = threadIdx.x;
    if (blockIdx.x >= KC) {
        // ---- conversion path ----
        int xb = blockIdx.x - KC;          // 0..312
        int cseg = t & 15, rloc = t >> 4;
        int c0 = cseg * 8;
        float is[8];
#pragma unroll
        for (int j = 0; j < 8; j++) {
            float psi = expf(log_psi[c0 + j]) + 1e-5f + 1e-4f;
            is[j] = 1.0f / psi;
        }
#pragma unroll
        for (int p = 0; p < 4; p++) {
            int r = xb*64 + p*16 + rloc;
            if (r < NPTS) {
                float xs[8];
                const float* xp = X + (size_t)r*DC + c0;
                *(float4*)&xs[0] = *(const float4*)xp;
                *(float4*)&xs[4] = *(const float4*)(xp + 4);
                bf16x8 hv;
                float s2 = 0.f;
#pragma unroll
                for (int j = 0; j < 8; j++) {
                    hv[j] = f2bf(xs[j]);
                    s2 = fmaf(xs[j]*is[j], xs[j], s2);
                }
                size_t fa = (size_t)(r >> 4)*2048 + (size_t)(cseg >> 2)*512
                          + (size_t)(cseg & 3)*128 + (size_t)(r & 15)*8;
                *(bf16x8*)(xH + fa) = hv;
                s2 += __shfl_xor(s2, 1, 16);
                s2 += __shfl_xor(s2, 2, 16);
                s2 += __shfl_xor(s2, 4, 16);
                s2 += __shfl_xor(s2, 8, 16);
                if (cseg == 0) s2g[r] = 0.5f * s2;
            }
        }
        return;
    }
    // ---- per-component Woodbury path ----
    int k = blockIdx.x;
    __shared__ float invpsiS[DC], muS[DC];
    __shared__ float lamR[DC*17];
    __shared__ float lamSc[DC*17];
    __shared__ float MS[QC*QC], LSm[QC*QC];
    __shared__ float invDS[QC];
    __shared__ float GT[QC*129];
    __shared__ float hS[QC];
    __shared__ float redS[4];
    __shared__ float hhS, ldS;

    float lp = 0.f, ipm = 0.f;
    if (t < DC) {
        float psi = expf(log_psi[t]) + 1e-5f + 1e-4f;
        float ip = 1.0f / psi;
        invpsiS[t] = ip;
        lp = logf(psi);
        float m = mu[k*DC + t];
        muS[t] = m;
        ipm = ip*m*m;
    }
    __syncthreads();
    for (int e = t; e < DC*QC; e += 256) {
        int d = e >> 4, q = e & 15;
        float lv = Lam[k*DC*QC + e];
        lamR[d*17 + q]  = lv;
        lamSc[d*17 + q] = lv * invpsiS[d];
    }
    __syncthreads();
    {   // M = I + Lam^T diag(invpsi) Lam
        int q = t >> 4, r = t & 15;
        float s0 = (q == r) ? 1.0f : 0.0f, s1 = 0.f, s2 = 0.f, s3 = 0.f;
#pragma unroll 1
        for (int d = 0; d < DC; d += 4) {
            s0 = fmaf(lamSc[(d+0)*17 + q], lamR[(d+0)*17 + r], s0);
            s1 = fmaf(lamSc[(d+1)*17 + q], lamR[(d+1)*17 + r], s1);
            s2 = fmaf(lamSc[(d+2)*17 + q], lamR[(d+2)*17 + r], s2);
            s3 = fmaf(lamSc[(d+3)*17 + q], lamR[(d+3)*17 + r], s3);
        }
        MS[q*QC + r] = (s0 + s1) + (s2 + s3);
    }
    __syncthreads();
    if (t < QC) {       // 16-lane shuffle Cholesky
        float m[QC], lrow[QC];
#pragma unroll
        for (int j = 0; j < QC; j++) m[j] = MS[t*QC + j];
#pragma unroll
        for (int j = 0; j < QC; j++) {
            float piv = __shfl(m[j], j, 16);
            float ljj = sqrtf(piv);
            float lij = m[j] / ljj;
            lrow[j] = lij;
#pragma unroll
            for (int r = j + 1; r < QC; r++)
                m[r] = fmaf(-lij, __shfl(lij, r, 16), m[r]);
        }
#pragma unroll
        for (int j = 0; j < QC; j++) LSm[t*QC + j] = lrow[j];
        invDS[t] = 1.0f / lrow[t];
        float ld = 2.0f * logf(lrow[t]);
        ld += __shfl_xor(ld, 1, 16);
        ld += __shfl_xor(ld, 2, 16);
        ld += __shfl_xor(ld, 4, 16);
        ld += __shfl_xor(ld, 8, 16);
        if (t == 0) ldS = ld;
    }
    __syncthreads();
    float g[QC];
    if (t < DC) {       // forward solve: column t of G
        float b[QC];
#pragma unroll
        for (int q = 0; q < QC; q++) b[q] = lamSc[t*17 + q];
#pragma unroll
        for (int i = 0; i < QC; i++) {
            float s = b[i];
#pragma unroll
            for (int x = 0; x < i; x++)
                s = fmaf(-LSm[i*QC + x], g[x], s);
            g[i] = s * invDS[i];
        }
        const float is2 = 0.70710678118654752f;
        int seg = t >> 3, w8 = t & 7;
#pragma unroll
        for (int q = 0; q < QC; q++) {
            GT[q*129 + t] = g[q];
            // pre-swizzled store: column seg -> seg ^ (gr&15), gr&15 == q
            btG[(k*QC + q)*DC + ((seg ^ q) << 3) + w8] = f2bf(g[q] * is2);
        }
    }
    __syncthreads();
    if (t < QC) {       // h = G mu
        float s = 0.f;
        for (int d = 0; d < DC; d++)
            s = fmaf(GT[t*129 + d], muS[d], s);
        hS[t] = s;
        float hh = s*s;
        hh += __shfl_xor(hh, 1, 16);
        hh += __shfl_xor(hh, 2, 16);
        hh += __shfl_xor(hh, 4, 16);
        hh += __shfl_xor(hh, 8, 16);
        if (t == 0) hhS = hh;
    }
    {
        float a = lp, b2 = ipm;
#pragma unroll
        for (int off = 1; off < 64; off <<= 1) {
            a  += __shfl_xor(a, off, 64);
            b2 += __shfl_xor(b2, off, 64);
        }
        if (t == 0)  { redS[0] = a; redS[1] = b2; }
        if (t == 64) { redS[2] = a; redS[3] = b2; }
    }
    __syncthreads();
    if (t < DC) {       // w' = invpsi*mu - G^T h  (pre-swizzled, key k&15)
        float gh = 0.f;
#pragma unroll
        for (int q = 0; q < QC; q++) gh = fmaf(g[q], hS[q], gh);
        float wp = invpsiS[t]*muS[t] - gh;
        int seg = t >> 3, w8 = t & 7;
        btG[(512 + k)*DC + ((seg ^ (k & 15)) << 3) + w8] = f2bf(wp);
    }
    if (t == 0) {
        const float log2pi = 1.8378770664093453f;
        float slp = redS[0] + redS[2];
        float tv  = redS[1] + redS[3];
        c2p[k] = log_pi[k]
            - 0.5f*((float)DC*log2pi + slp + ldS + tv) + 0.5f*hhS;
    }
}

// ---------------------------------------------------------------------------
// Kernel 2: all-components MFMA GEMM + fused logsumexp. Grid 313 (ALL
// co-resident at 2 blocks/CU). Block = 4 waves x 16 rows = 64 rows x all 32
// comps. B staged in two 272-row halves (16 comps' G + their w') via
// global_load_lds into one 69.6 KB buffer (global pre-swizzled -> linear
// dest, XOR on read). Epilogue -> lr LDS [64][33]; in-block logsumexp.
// ---------------------------------------------------------------------------
__global__ __launch_bounds__(256, 2) void mfa_gemm(
    const short* __restrict__ xH, const float* __restrict__ s2g,
    const float* __restrict__ c2p, const short* __restrict__ btG,
    float* __restrict__ out)
{
    __shared__ __align__(16) char ldsB[272*256];     // 69632 B
    __shared__ float ldsLR[64*33];                   // 8448 B
    int t = threadIdx.x;
    int w = t >> 6, l = t & 63;
    int m16 = l & 15, g4 = l >> 4;
    int xb = blockIdx.x;
    int rb0 = xb*64 + w*16;

    // A fragments: fragment-major, wave-uniform clamped tile (1KB loads)
    int tile16 = min(xb*4 + w, (NPTS >> 4) - 1);
    const short* ph = xH + (size_t)tile16*2048 + g4*128 + m16*8;
    bf16x8 aH[4];
#pragma unroll
    for (int ks = 0; ks < 4; ks++)
        aH[ks] = *(const bf16x8*)(ph + ks*512);
    float s2p = s2g[min(rb0 + m16, NPTS - 1)];

#pragma unroll 1
    for (int h = 0; h < 2; h++) {
        if (h) __syncthreads();          // prior half's reads done
        // ---- stage half h: 1088 chunks/wave via global_load_lds ----
#pragma unroll
        for (int i = 0; i < 17; i++) {
            int c = w*1088 + i*64 + l;
            int row = c >> 4, seg = c & 15;
            int gr = (row < 256) ? (h*256 + row) : (512 + h*16 + (row - 256));
            const short* gsrc = btG + (size_t)gr*DC + seg*8;
            __builtin_amdgcn_global_load_lds(
                (const __attribute__((address_space(1))) unsigned int*)gsrc,
                (__attribute__((address_space(3))) unsigned int*)
                    (ldsB + (size_t)(w*1088 + i*64)*16),
                16, 0, 0);
        }
        __syncthreads();

        // ---- compute: 16 G-tiles + 1 w'-tile ----
        f32x4 acc[16], accw;
#pragma unroll
        for (int i = 0; i < 16; i++) acc[i] = (f32x4){0.f, 0.f, 0.f, 0.f};
        accw = (f32x4){0.f, 0.f, 0.f, 0.f};
#pragma unroll
        for (int nt = 0; nt < 16; nt++) {
            unsigned row = (unsigned)(nt*16 + m16);
            unsigned rbse = row << 8, sw = row & 15u;
#pragma unroll
            for (int ks = 0; ks < 4; ks++) {
                unsigned bo = rbse + ((((unsigned)(ks*4 + g4)) ^ sw) << 4);
                bf16x8 bh = *(const bf16x8*)(ldsB + bo);
                acc[nt] = __builtin_amdgcn_mfma_f32_16x16x32_bf16(aH[ks], bh, acc[nt], 0, 0, 0);
            }
        }
        {
            unsigned row = (unsigned)(256 + m16);
            unsigned rbse = row << 8, sw = row & 15u;
#pragma unroll
            for (int ks = 0; ks < 4; ks++) {
                unsigned bo = rbse + ((((unsigned)(ks*4 + g4)) ^ sw) << 4);
                bf16x8 bh = *(const bf16x8*)(ldsB + bo);
                accw = __builtin_amdgcn_mfma_f32_16x16x32_bf16(aH[ks], bh, accw, 0, 0, 0);
            }
        }

        // ---- epilogue: lr -> ldsLR ----
#pragma unroll
        for (int nt = 0; nt < 16; nt++) {
            int k = h*16 + nt;
            float c2v = c2p[k];
#pragma unroll
            for (int j = 0; j < 4; j++) {
                float v = acc[nt][j]*acc[nt][j];
                v += __shfl_xor(v, 1, 64);
                v += __shfl_xor(v, 2, 64);
                v += __shfl_xor(v, 4, 64);
                v += __shfl_xor(v, 8, 64);
                float s2j = __shfl(s2p, (l & 48) | (g4*4 + j), 64);
                if (m16 == nt)
                    ldsLR[(w*16 + g4*4 + j)*33 + k] = c2v + accw[j] - s2j + v;
            }
        }
    }
    __syncthreads();

    // ---- fused logsumexp: thread t -> (row t>>2, octet t&3) ----
    {
        int rl = t >> 2, oct = t & 3;
        int grow = xb*64 + rl;
        float v[8];
        const float* rp = ldsLR + rl*33 + oct*8;
#pragma unroll
        for (int j = 0; j < 8; j++) v[j] = rp[j];
        float m = v[0];
#pragma unroll
        for (int j = 1; j < 8; j++) m = fmaxf(m, v[j]);
        m = fmaxf(m, __shfl_xor(m, 1, 64));
        m = fmaxf(m, __shfl_xor(m, 2, 64));
        float s = 0.f;
#pragma unroll
        for (int j = 0; j < 8; j++) s += expf(v[j] - m);
        s += __shfl_xor(s, 1, 64);
        s += __shfl_xor(s, 2, 64);
        float ll = m + logf(s);
        if (grow < NPTS) {
            float o[8];
#pragma unroll
            for (int j = 0; j < 8; j++) o[j] = v[j] - ll;
            float* op = out + (size_t)grow*KC + oct*8;
            *(float4*)op       = *(const float4*)&o[0];
            *(float4*)(op + 4) = *(const float4*)&o[4];
            if (oct == 0) out[(size_t)NPTS*KC + grow] = ll;
        }
    }
}

extern "C" void kernel_launch(void* const* d_in, const int* in_sizes, int n_in,
                              void* d_out, int out_size, void* d_ws, size_t ws_size,
                              hipStream_t stream)
{
    const float* X       = (const float*)d_in[0];
    const float* log_pi  = (const float*)d_in[1];
    const float* mu      = (const float*)d_in[2];
    const float* Lam     = (const float*)d_in[3];
    const float* log_psi = (const float*)d_in[4];
    float* out = (float*)d_out;
    char* wsb = (char*)d_ws;
    float* c2p = (float*)(wsb + WS_C2P_B);
    short* btG = (short*)(wsb + WS_BTG_B);
    float* s2g = (float*)(wsb + WS_S2_B);
    short* xH  = (short*)(wsb + WS_XH_B);

    hipLaunchKernelGGL(mfa_prep, dim3(KC + 313), dim3(256), 0, stream,
                       X, log_pi, mu, Lam, log_psi, c2p, btG, xH, s2g);
    hipLaunchKernelGGL(mfa_gemm, dim3(313), dim3(256), 0, stream,
                       xH, s2g, c2p, btG, out);
}

// Round 15
// 24.783 us; speedup vs baseline: 1.7115x; 1.7115x over previous
//
#include <hip/hip_runtime.h>
#include <hip/hip_bf16.h>
#include <math.h>

#define KC 32
#define DC 128
#define QC 16
#define NPTS 20000

// ws layout (bytes):
//   c2p[32] f32        @ 0
//   btG[544*128] bf16  @ 128     (PRE-SWIZZLED: elem (gr,col) at seg^(gr&15))
//   s2h[20000] f32     @ 139392  (0.5 * x^T invpsi x)
//   XH[1250*2048] s    @ 219520  (fragment-major bf16 X)
#define WS_C2P_B 0
#define WS_BTG_B 128
#define WS_S2_B  139392
#define WS_XH_B  219520

typedef __attribute__((ext_vector_type(8))) short bf16x8;
typedef __attribute__((ext_vector_type(4))) float f32x4;

// round-to-nearest-even bf16
static __device__ __forceinline__ short f2bf(float x) {
    union { float f; unsigned u; } v; v.f = x;
    unsigned r = v.u + 0x7fffu + ((v.u >> 16) & 1u);
    return (short)(r >> 16);
}

// ---------------------------------------------------------------------------
// Kernel 1 (fused prep): blocks 0..31 per-component Woodbury precompute
// (G/sqrt2 + w' rows, bf16, PRE-SWIZZLED column layout; C2'); blocks 32+
// convert 64 X rows each to bf16 fragment-major and store 0.5*x^T invpsi x.
// ---------------------------------------------------------------------------
__global__ __launch_bounds__(256) void mfa_prep(
    const float* __restrict__ X, const float* __restrict__ log_pi,
    const float* __restrict__ mu, const float* __restrict__ Lam,
    const float* __restrict__ log_psi,
    float* __restrict__ c2p, short* __restrict__ btG,
    short* __restrict__ xH, float* __restrict__ s2g)
{
    int t = threadIdx.x;
    if (blockIdx.x >= KC) {
        // ---- conversion path ----
        int xb = blockIdx.x - KC;          // 0..312
        int cseg = t & 15, rloc = t >> 4;
        int c0 = cseg * 8;
        float is[8];
#pragma unroll
        for (int j = 0; j < 8; j++) {
            float psi = expf(log_psi[c0 + j]) + 1e-5f + 1e-4f;
            is[j] = 1.0f / psi;
        }
#pragma unroll
        for (int p = 0; p < 4; p++) {
            int r = xb*64 + p*16 + rloc;
            if (r < NPTS) {
                float xs[8];
                const float* xp = X + (size_t)r*DC + c0;
                *(float4*)&xs[0] = *(const float4*)xp;
                *(float4*)&xs[4] = *(const float4*)(xp + 4);
                bf16x8 hv;
                float s2 = 0.f;
#pragma unroll
                for (int j = 0; j < 8; j++) {
                    hv[j] = f2bf(xs[j]);
                    s2 = fmaf(xs[j]*is[j], xs[j], s2);
                }
                size_t fa = (size_t)(r >> 4)*2048 + (size_t)(cseg >> 2)*512
                          + (size_t)(cseg & 3)*128 + (size_t)(r & 15)*8;
                *(bf16x8*)(xH + fa) = hv;
                s2 += __shfl_xor(s2, 1, 16);
                s2 += __shfl_xor(s2, 2, 16);
                s2 += __shfl_xor(s2, 4, 16);
                s2 += __shfl_xor(s2, 8, 16);
                if (cseg == 0) s2g[r] = 0.5f * s2;
            }
        }
        return;
    }
    // ---- per-component Woodbury path ----
    int k = blockIdx.x;
    __shared__ float invpsiS[DC], muS[DC];
    __shared__ float lamR[DC*17];
    __shared__ float lamSc[DC*17];
    __shared__ float MS[QC*QC], LSm[QC*QC];
    __shared__ float invDS[QC];
    __shared__ float GT[QC*129];
    __shared__ float hS[QC];
    __shared__ float redS[4];
    __shared__ float hhS, ldS;

    float lp = 0.f, ipm = 0.f;
    if (t < DC) {
        float psi = expf(log_psi[t]) + 1e-5f + 1e-4f;
        float ip = 1.0f / psi;
        invpsiS[t] = ip;
        lp = logf(psi);
        float m = mu[k*DC + t];
        muS[t] = m;
        ipm = ip*m*m;
    }
    __syncthreads();
    for (int e = t; e < DC*QC; e += 256) {
        int d = e >> 4, q = e & 15;
        float lv = Lam[k*DC*QC + e];
        lamR[d*17 + q]  = lv;
        lamSc[d*17 + q] = lv * invpsiS[d];
    }
    __syncthreads();
    {   // M = I + Lam^T diag(invpsi) Lam
        int q = t >> 4, r = t & 15;
        float s0 = (q == r) ? 1.0f : 0.0f, s1 = 0.f, s2 = 0.f, s3 = 0.f;
#pragma unroll 1
        for (int d = 0; d < DC; d += 4) {
            s0 = fmaf(lamSc[(d+0)*17 + q], lamR[(d+0)*17 + r], s0);
            s1 = fmaf(lamSc[(d+1)*17 + q], lamR[(d+1)*17 + r], s1);
            s2 = fmaf(lamSc[(d+2)*17 + q], lamR[(d+2)*17 + r], s2);
            s3 = fmaf(lamSc[(d+3)*17 + q], lamR[(d+3)*17 + r], s3);
        }
        MS[q*QC + r] = (s0 + s1) + (s2 + s3);
    }
    __syncthreads();
    if (t < QC) {       // 16-lane shuffle Cholesky
        float m[QC], lrow[QC];
#pragma unroll
        for (int j = 0; j < QC; j++) m[j] = MS[t*QC + j];
#pragma unroll
        for (int j = 0; j < QC; j++) {
            float piv = __shfl(m[j], j, 16);
            float ljj = sqrtf(piv);
            float lij = m[j] / ljj;
            lrow[j] = lij;
#pragma unroll
            for (int r = j + 1; r < QC; r++)
                m[r] = fmaf(-lij, __shfl(lij, r, 16), m[r]);
        }
#pragma unroll
        for (int j = 0; j < QC; j++) LSm[t*QC + j] = lrow[j];
        invDS[t] = 1.0f / lrow[t];
        float ld = 2.0f * logf(lrow[t]);
        ld += __shfl_xor(ld, 1, 16);
        ld += __shfl_xor(ld, 2, 16);
        ld += __shfl_xor(ld, 4, 16);
        ld += __shfl_xor(ld, 8, 16);
        if (t == 0) ldS = ld;
    }
    __syncthreads();
    float g[QC];
    if (t < DC) {       // forward solve: column t of G
        float b[QC];
#pragma unroll
        for (int q = 0; q < QC; q++) b[q] = lamSc[t*17 + q];
#pragma unroll
        for (int i = 0; i < QC; i++) {
            float s = b[i];
#pragma unroll
            for (int x = 0; x < i; x++)
                s = fmaf(-LSm[i*QC + x], g[x], s);
            g[i] = s * invDS[i];
        }
        const float is2 = 0.70710678118654752f;
        int seg = t >> 3, w8 = t & 7;
#pragma unroll
        for (int q = 0; q < QC; q++) {
            GT[q*129 + t] = g[q];
            // pre-swizzled store: column seg -> seg ^ (gr&15), gr&15 == q
            btG[(k*QC + q)*DC + ((seg ^ q) << 3) + w8] = f2bf(g[q] * is2);
        }
    }
    __syncthreads();
    if (t < QC) {       // h = G mu
        float s = 0.f;
        for (int d = 0; d < DC; d++)
            s = fmaf(GT[t*129 + d], muS[d], s);
        hS[t] = s;
        float hh = s*s;
        hh += __shfl_xor(hh, 1, 16);
        hh += __shfl_xor(hh, 2, 16);
        hh += __shfl_xor(hh, 4, 16);
        hh += __shfl_xor(hh, 8, 16);
        if (t == 0) hhS = hh;
    }
    {
        float a = lp, b2 = ipm;
#pragma unroll
        for (int off = 1; off < 64; off <<= 1) {
            a  += __shfl_xor(a, off, 64);
            b2 += __shfl_xor(b2, off, 64);
        }
        if (t == 0)  { redS[0] = a; redS[1] = b2; }
        if (t == 64) { redS[2] = a; redS[3] = b2; }
    }
    __syncthreads();
    if (t < DC) {       // w' = invpsi*mu - G^T h  (pre-swizzled, key k&15)
        float gh = 0.f;
#pragma unroll
        for (int q = 0; q < QC; q++) gh = fmaf(g[q], hS[q], gh);
        float wp = invpsiS[t]*muS[t] - gh;
        int seg = t >> 3, w8 = t & 7;
        btG[(512 + k)*DC + ((seg ^ (k & 15)) << 3) + w8] = f2bf(wp);
    }
    if (t == 0) {
        const float log2pi = 1.8378770664093453f;
        float slp = redS[0] + redS[2];
        float tv  = redS[1] + redS[3];
        c2p[k] = log_pi[k]
            - 0.5f*((float)DC*log2pi + slp + ldS + tv) + 0.5f*hhS;
    }
}

// ---------------------------------------------------------------------------
// Kernel 2: all-components MFMA GEMM + in-register logsumexp. Grid 313.
// SWAPPED operands: mfma(G_tile, X_frag) -> acc(row=q, col=n). The q-sum is
// 3 in-lane FMAs + 2 shuffles per component (vs 4-deep butterflies).
// B staged in two 272-row halves via global_load_lds (pre-swizzled global,
// linear dest, XOR on read). lr kept in regs; LSE via 4 shuffles; coalesced
// ll store. No ldsLR, no extra barriers, no norm kernel.
// ---------------------------------------------------------------------------
#define HALF_PASS(HH, LRA) do {                                               \
    _Pragma("unroll")                                                         \
    for (int i = 0; i < 17; i++) {                                            \
        int c = w*1088 + i*64 + l;                                            \
        int row = c >> 4, seg = c & 15;                                       \
        int gr = (row < 256) ? ((HH)*256 + row) : (512 + (HH)*16 + (row-256));\
        const short* gsrc = btG + (size_t)gr*DC + seg*8;                      \
        __builtin_amdgcn_global_load_lds(                                     \
            (const __attribute__((address_space(1))) unsigned int*)gsrc,      \
            (__attribute__((address_space(3))) unsigned int*)                 \
                (ldsB + (size_t)(w*1088 + i*64)*16),                          \
            16, 0, 0);                                                        \
    }                                                                         \
    __syncthreads();                                                          \
    float quad[16];                                                           \
    _Pragma("unroll")                                                         \
    for (int nt = 0; nt < 16; nt++) {                                         \
        f32x4 acc = (f32x4){0.f, 0.f, 0.f, 0.f};                              \
        unsigned brow = (unsigned)(nt*16 + m16);                              \
        unsigned rbse = brow << 8, sw = brow & 15u;                           \
        _Pragma("unroll")                                                     \
        for (int ks = 0; ks < 4; ks++) {                                      \
            unsigned bo = rbse + ((((unsigned)(ks*4 + g4)) ^ sw) << 4);       \
            bf16x8 bh = *(const bf16x8*)(ldsB + bo);                          \
            acc = __builtin_amdgcn_mfma_f32_16x16x32_bf16(bh, aH[ks], acc, 0, 0, 0); \
        }                                                                     \
        float sq = acc[0]*acc[0];                                             \
        sq = fmaf(acc[1], acc[1], sq);                                        \
        sq = fmaf(acc[2], acc[2], sq);                                        \
        sq = fmaf(acc[3], acc[3], sq);                                        \
        sq += __shfl_xor(sq, 16, 64);                                         \
        sq += __shfl_xor(sq, 32, 64);                                         \
        quad[nt] = sq;                                                        \
    }                                                                         \
    f32x4 accw = (f32x4){0.f, 0.f, 0.f, 0.f};                                 \
    {                                                                         \
        unsigned brow = (unsigned)(256 + m16);                                \
        unsigned rbse = brow << 8, sw = brow & 15u;                           \
        _Pragma("unroll")                                                     \
        for (int ks = 0; ks < 4; ks++) {                                      \
            unsigned bo = rbse + ((((unsigned)(ks*4 + g4)) ^ sw) << 4);       \
            bf16x8 bh = *(const bf16x8*)(ldsB + bo);                          \
            accw = __builtin_amdgcn_mfma_f32_16x16x32_bf16(bh, aH[ks], accw, 0, 0, 0); \
        }                                                                     \
    }                                                                         \
    float4 c2v = *(const float4*)(c2p + (HH)*16 + g4*4);                      \
    _Pragma("unroll")                                                         \
    for (int j = 0; j < 4; j++) {                                             \
        float qv = (g4 == 0) ? quad[j] : (g4 == 1) ? quad[4+j]                \
                 : (g4 == 2) ? quad[8+j] : quad[12+j];                        \
        float c2j = (j == 0) ? c2v.x : (j == 1) ? c2v.y                       \
                  : (j == 2) ? c2v.z : c2v.w;                                 \
        LRA[j] = c2j + accw[j] - s2p + qv;                                    \
    }                                                                         \
} while (0)

__global__ __launch_bounds__(256, 2) void mfa_gemm(
    const short* __restrict__ xH, const float* __restrict__ s2g,
    const float* __restrict__ c2p, const short* __restrict__ btG,
    float* __restrict__ out)
{
    __shared__ __align__(16) char ldsB[272*256];     // 69632 B
    int t = threadIdx.x;
    int w = t >> 6, l = t & 63;
    int m16 = l & 15, g4 = l >> 4;
    int xb = blockIdx.x;
    int rb0 = xb*64 + w*16;

    // X fragments (used as the B-operand after the swap; layout symmetric)
    int tile16 = min(xb*4 + w, (NPTS >> 4) - 1);
    const short* ph = xH + (size_t)tile16*2048 + g4*128 + m16*8;
    bf16x8 aH[4];
#pragma unroll
    for (int ks = 0; ks < 4; ks++)
        aH[ks] = *(const bf16x8*)(ph + ks*512);
    float s2p = s2g[min(rb0 + m16, NPTS - 1)];

    float lrA[4], lrB[4];
    HALF_PASS(0, lrA);
    __syncthreads();                 // half-0 reads done before restage
    HALF_PASS(1, lrB);

    // ---- in-register logsumexp over k (8 local + 2 cross-lane steps) ----
    float mx = fmaxf(fmaxf(fmaxf(lrA[0], lrA[1]), fmaxf(lrA[2], lrA[3])),
                     fmaxf(fmaxf(lrB[0], lrB[1]), fmaxf(lrB[2], lrB[3])));
    mx = fmaxf(mx, __shfl_xor(mx, 16, 64));
    mx = fmaxf(mx, __shfl_xor(mx, 32, 64));
    float s = 0.f;
#pragma unroll
    for (int j = 0; j < 4; j++) s += expf(lrA[j] - mx);
#pragma unroll
    for (int j = 0; j < 4; j++) s += expf(lrB[j] - mx);
    s += __shfl_xor(s, 16, 64);
    s += __shfl_xor(s, 32, 64);
    float ll = mx + logf(s);

    int grow = rb0 + m16;
    if (grow < NPTS) {
        float4 o0, o1;
        o0.x = lrA[0] - ll; o0.y = lrA[1] - ll;
        o0.z = lrA[2] - ll; o0.w = lrA[3] - ll;
        o1.x = lrB[0] - ll; o1.y = lrB[1] - ll;
        o1.z = lrB[2] - ll; o1.w = lrB[3] - ll;
        float* op = out + (size_t)grow*KC;
        *(float4*)(op + g4*4)      = o0;
        *(float4*)(op + 16 + g4*4) = o1;
        if (g4 == 0) out[(size_t)NPTS*KC + grow] = ll;
    }
}

extern "C" void kernel_launch(void* const* d_in, const int* in_sizes, int n_in,
                              void* d_out, int out_size, void* d_ws, size_t ws_size,
                              hipStream_t stream)
{
    const float* X       = (const float*)d_in[0];
    const float* log_pi  = (const float*)d_in[1];
    const float* mu      = (const float*)d_in[2];
    const float* Lam     = (const float*)d_in[3];
    const float* log_psi = (const float*)d_in[4];
    float* out = (float*)d_out;
    char* wsb = (char*)d_ws;
    float* c2p = (float*)(wsb + WS_C2P_B);
    short* btG = (short*)(wsb + WS_BTG_B);
    float* s2g = (float*)(wsb + WS_S2_B);
    short* xH  = (short*)(wsb + WS_XH_B);

    hipLaunchKernelGGL(mfa_prep, dim3(KC + 313), dim3(256), 0, stream,
                       X, log_pi, mu, Lam, log_psi, c2p, btG, xH, s2g);
    hipLaunchKernelGGL(mfa_gemm, dim3(313), dim3(256), 0, stream,
                       xH, s2g, c2p, btG, out);
}